// Round 5
// baseline (780.003 us; speedup 1.0000x reference)
//
#include <hip/hip_runtime.h>
#include <hip/hip_bf16.h>
#include <stdint.h>

#define NG 128
#define EPSI 1e-5f

typedef __attribute__((ext_vector_type(8))) __bf16 bf16x8;
typedef __attribute__((ext_vector_type(4))) float f32x4;

union ABFrag { bf16x8 v; unsigned short u[8]; uint4 q; };
union U8 { uint4 q; unsigned short u[8]; };

__device__ __forceinline__ float b2f(unsigned short u){
  union { unsigned int i; float f; } v; v.i = ((unsigned int)u) << 16; return v.f;
}
__device__ __forceinline__ unsigned short f2b(float f){
  union { float f; unsigned int i; } v; v.f = f;
  unsigned int r = v.i + 0x7fffu + ((v.i >> 16) & 1u);
  return (unsigned short)(r >> 16);
}
// pack 2 f32 -> 2 bf16 (RNE), lo in bits[15:0], hi in bits[31:16]
__device__ __forceinline__ unsigned int pk2(float lo, float hi){
  unsigned int r;
  asm("v_cvt_pk_bf16_f32 %0, %1, %2" : "=v"(r) : "v"(lo), "v"(hi));
  return r;
}

// ---------------- prep: bf16 conversions (frag order), graph hist, node hist ----------------
__global__ void kprep(const float* __restrict__ emb, const float* __restrict__ W1,
                      const float* __restrict__ W2,
                      const int* __restrict__ ei, const int* __restrict__ batch,
                      unsigned short* __restrict__ embb, unsigned short* __restrict__ WcF,
                      unsigned short* __restrict__ W2F, unsigned int* __restrict__ hist,
                      unsigned int* __restrict__ nodeh, int N, int E){
  __shared__ unsigned int h[NG];
  for (int i = threadIdx.x; i < NG; i += 256) h[i] = 0;
  __syncthreads();
  int idx = blockIdx.x * 256 + threadIdx.x;
  int stride = gridDim.x * 256;
  int embCnt4 = N * 16;  // float4 groups
  for (int i = idx; i < embCnt4; i += stride){
    float4 v = *(const float4*)(emb + (size_t)i * 4);
    ushort4 o; o.x = f2b(v.x); o.y = f2b(v.y); o.z = f2b(v.z); o.w = f2b(v.w);
    *(ushort4*)(embb + (size_t)i * 4) = o;
  }
  for (int i = idx; i < 32 * 2 * 64 * 8; i += stride){
    int j = i & 7, lane = (i >> 3) & 63, ks = (i >> 9) & 1, tn = i >> 10;
    int quad = lane >> 4, l15 = lane & 15;
    int k = ks * 32 + quad * 8 + j;
    int n = tn * 16 + l15;
    float wv = (n < 256) ? W1[k * 256 + n] : W1[(k + 64) * 256 + (n - 256)];
    WcF[i] = f2b(wv);
  }
  for (int i = idx; i < 4 * 8 * 64 * 8; i += stride){
    int j = i & 7, lane = (i >> 3) & 63, ks = (i >> 9) & 7, w = i >> 12;
    int quad = lane >> 4, l15 = lane & 15;
    W2F[i] = f2b(W2[(ks * 32 + quad * 8 + j) * 64 + w * 16 + l15]);
  }
  for (int e = idx; e < E; e += stride){
    int cn = ei[e];
    atomicAdd(&h[batch[cn]], 1u);
    atomicAdd(&nodeh[cn], 1u);
  }
  __syncthreads();
  for (int i = threadIdx.x; i < NG; i += 256)
    if (h[i]) atomicAdd(&hist[i], h[i]);
}

// --- scan: one block per graph. Computes padded-base prefix (pbase) from hist,
//     binary-searches this graph's node range in sorted batch, then exclusive-scans
//     nodeh over that range into ncursor (= pbase + local prefix). ---
__global__ void __launch_bounds__(256) kscan(const unsigned int* __restrict__ nodeh,
                      const unsigned int* __restrict__ hist,
                      const int* __restrict__ batch,
                      unsigned int* __restrict__ ncursor,
                      unsigned int* __restrict__ gmeta, int N){
  __shared__ unsigned int sh[3];     // pbase, lo, hi
  __shared__ unsigned int wtot[4];
  int g = blockIdx.x;
  int t = threadIdx.x;
  // padded-count prefix over graphs < g (redundant per block; trivial work)
  unsigned int part = 0;
  for (int i = t; i < g; i += 256) part += (hist[i] + 31u) & ~31u;
  #pragma unroll
  for (int d = 1; d < 64; d <<= 1) part += __shfl_xor(part, d);
  if ((t & 63) == 0) wtot[t >> 6] = part;
  // node range via binary search on sorted batch
  if (t == 64 || t == 65){
    int target = g + (t - 64);
    int lo = 0, hi = N;
    while (lo < hi){ int mid = (lo + hi) >> 1; if (batch[mid] < target) lo = mid + 1; else hi = mid; }
    sh[1 + (t - 64)] = lo;
  }
  __syncthreads();
  if (t == 0){
    unsigned int pb = wtot[0] + wtot[1] + wtot[2] + wtot[3];
    sh[0] = pb;
    gmeta[g] = pb;
    if (g == NG - 1) gmeta[NG] = pb + ((hist[g] + 31u) & ~31u);
  }
  __syncthreads();
  unsigned int run = sh[0];
  int lo = (int)sh[1], hi = (int)sh[2];
  int wid = t >> 6;
  for (int base = lo; base < hi; base += 256){
    int i = base + t;
    unsigned int v = (i < hi) ? nodeh[i] : 0u;
    unsigned int x = v;
    #pragma unroll
    for (int d = 1; d < 64; d <<= 1){
      unsigned int y = __shfl_up(x, d);
      if ((t & 63) >= d) x += y;
    }
    if ((t & 63) == 63) wtot[wid] = x;
    __syncthreads();
    unsigned int woff = 0;
    #pragma unroll
    for (int wb = 0; wb < 4; ++wb) if (wb < wid) woff += wtot[wb];
    if (i < hi) ncursor[i] = run + woff + x - v;
    run += wtot[0] + wtot[1] + wtot[2] + wtot[3];
    __syncthreads();
  }
}

// einfo[p] = {col_node, row_node, graph, orig_edge}, p sorted by col node (=> by graph),
// graph segments padded to multiples of 32.
__global__ void kscatter(const int* __restrict__ ei, const int* __restrict__ batch, int E,
                         unsigned int* __restrict__ ncursor, int4* __restrict__ einfo){
  int idx = blockIdx.x * 256 + threadIdx.x;
  for (int e = idx; e < E; e += gridDim.x * 256){
    int cn = ei[e], rn = ei[E + e];
    int g = batch[cn];
    unsigned int p = atomicAdd(&ncursor[cn], 1u);
    einfo[p] = make_int4(cn, rn, g, e);
  }
}

// fill pad slots with a copy of the graph's first edge, orig = -1 (one block per graph)
__global__ void kpad(int4* __restrict__ einfo, const unsigned int* __restrict__ hist,
                     const unsigned int* __restrict__ gmeta){
  int g = blockIdx.x;
  unsigned int cnt = hist[g];
  if (!cnt) return;
  unsigned int pe = (cnt + 31u) & ~31u;
  if (cnt == pe) return;
  unsigned int base = gmeta[g];
  int4 e0 = einfo[base]; e0.w = -1;
  for (unsigned int i = cnt + threadIdx.x; i < pe; i += 64)
    einfo[base + i] = e0;
}

// ---------------- GEMM1: PQ[N,512] = embb[N,64] @ W1cat[64,512] (+b1 on P cols) ----------------
__global__ void __launch_bounds__(256) kgemm1(const unsigned short* __restrict__ embb,
    const unsigned short* __restrict__ WcF, const float* __restrict__ b1,
    unsigned short* __restrict__ PQb, int Nn){
  int wave = threadIdx.x >> 6, lane = threadIdx.x & 63;
  int quad = lane >> 4, l15 = lane & 15;
  int t = blockIdx.x * 4 + wave;
  int tmmax = (Nn + 15) >> 4;
  int tm = t >> 5, tn = t & 31;
  if (tm >= tmmax) return;
  int m = tm * 16 + l15; if (m >= Nn) m = Nn - 1;
  f32x4 acc = {0.f, 0.f, 0.f, 0.f};
  #pragma unroll
  for (int ks = 0; ks < 2; ++ks){
    ABFrag a, b;
    a.q = *(const uint4*)(embb + (size_t)m * 64 + ks * 32 + quad * 8);
    b.q = *(const uint4*)(WcF + ((size_t)(tn * 2 + ks) * 64 + lane) * 8);
    acc = __builtin_amdgcn_mfma_f32_16x16x32_bf16(a.v, b.v, acc, 0, 0, 0);
  }
  int col = tn * 16 + l15;
  float bias = (col < 256) ? b1[col] : 0.0f;
  #pragma unroll
  for (int r = 0; r < 4; ++r){
    int rowg = tm * 16 + quad * 4 + r;
    if (rowg < Nn) PQb[(size_t)rowg * 512 + col] = f2b(acc[r] + bias);
  }
}

// ------- stats over y1 = P[col]+Q[row]; contiguous 512-edge chunk/block, LDS accumulate -----
// 4 edges in flight per thread (8 gathers) for memory-level parallelism.
__global__ void __launch_bounds__(256) kstats1(const unsigned short* __restrict__ PQb,
                        const int4* __restrict__ einfo, const unsigned int* __restrict__ gmeta,
                        float* __restrict__ sum1, float* __restrict__ sq1){
  __shared__ float lsum[8][256];
  __shared__ float lsq[8][256];
  int tid = threadIdx.x;
  int EP = (int)gmeta[NG];
  int i0 = blockIdx.x * 512;
  if (i0 >= EP) return;
  for (int i = tid; i < 8 * 256; i += 256){ ((float*)lsum)[i] = 0.f; ((float*)lsq)[i] = 0.f; }
  __syncthreads();
  int i1 = min(EP, i0 + 512);
  int gfirst = einfo[i0].z;
  int eo = tid >> 5;          // 8 edge slots
  int c8 = (tid & 31) * 8;    // 8-channel slice
  float s[8], q[8];
  #pragma unroll
  for (int t = 0; t < 8; ++t){ s[t] = 0.f; q[t] = 0.f; }
  int cur = -1;
  auto flushreg = [&](){
    if (cur >= 0){
      unsigned slot = (unsigned)(cur - gfirst);
      if (slot < 8u){
        #pragma unroll
        for (int t = 0; t < 8; ++t){
          atomicAdd(&lsum[slot][c8 + t], s[t]);
          atomicAdd(&lsq[slot][c8 + t], q[t]);
        }
      } else {
        #pragma unroll
        for (int t = 0; t < 8; ++t){
          atomicAdd(&sum1[cur * 256 + c8 + t], s[t]);
          atomicAdd(&sq1[cur * 256 + c8 + t], q[t]);
        }
      }
      #pragma unroll
      for (int t = 0; t < 8; ++t){ s[t] = 0.f; q[t] = 0.f; }
    }
  };
  auto accum = [&](const U8& pu, const U8& qu){
    #pragma unroll
    for (int t = 0; t < 8; ++t){
      float y = b2f(pu.u[t]) + b2f(qu.u[t]);
      s[t] += y; q[t] += y * y;
    }
  };
  for (int p = i0 + eo; p < i1; p += 32){
    int4 ev0 = einfo[p];
    int pa = p + 8, pb = p + 16, pc = p + 24;
    int4 ev1 = (pa < i1) ? einfo[pa] : make_int4(0, 0, -1, -1);
    int4 ev2 = (pb < i1) ? einfo[pb] : make_int4(0, 0, -1, -1);
    int4 ev3 = (pc < i1) ? einfo[pc] : make_int4(0, 0, -1, -1);
    U8 pu0, qu0, pu1, qu1, pu2, qu2, pu3, qu3;
    pu0.q = *(const uint4*)(PQb + (size_t)ev0.x * 512 + c8);
    qu0.q = *(const uint4*)(PQb + (size_t)ev0.y * 512 + 256 + c8);
    pu1.q = *(const uint4*)(PQb + (size_t)ev1.x * 512 + c8);
    qu1.q = *(const uint4*)(PQb + (size_t)ev1.y * 512 + 256 + c8);
    pu2.q = *(const uint4*)(PQb + (size_t)ev2.x * 512 + c8);
    qu2.q = *(const uint4*)(PQb + (size_t)ev2.y * 512 + 256 + c8);
    pu3.q = *(const uint4*)(PQb + (size_t)ev3.x * 512 + c8);
    qu3.q = *(const uint4*)(PQb + (size_t)ev3.y * 512 + 256 + c8);
    if (ev0.z != cur){ flushreg(); cur = ev0.z; }
    if (ev0.w >= 0) accum(pu0, qu0);
    if (ev1.z >= 0){
      if (ev1.z != cur){ flushreg(); cur = ev1.z; }
      if (ev1.w >= 0) accum(pu1, qu1);
    }
    if (ev2.z >= 0){
      if (ev2.z != cur){ flushreg(); cur = ev2.z; }
      if (ev2.w >= 0) accum(pu2, qu2);
    }
    if (ev3.z >= 0){
      if (ev3.z != cur){ flushreg(); cur = ev3.z; }
      if (ev3.w >= 0) accum(pu3, qu3);
    }
  }
  flushreg();
  __syncthreads();
  for (int i = tid; i < 8 * 256; i += 256){
    int slot = i >> 8, ch = i & 255;
    float vs = lsum[slot][ch], vq = lsq[slot][ch];
    if (vs != 0.f || vq != 0.f){
      int g = gfirst + slot;
      atomicAdd(&sum1[g * 256 + ch], vs);
      atomicAdd(&sq1[g * 256 + ch], vq);
    }
  }
}

__global__ void kfin(const float* __restrict__ sum, const float* __restrict__ sq,
                     const unsigned int* __restrict__ hist,
                     float* __restrict__ meanA, float* __restrict__ rstdA, int C){
  int i = blockIdx.x * blockDim.x + threadIdx.x;
  if (i >= NG * C) return;
  int g = i / C;
  float cnt = fmaxf((float)hist[g], 1.0f);
  float m = sum[i] / cnt;
  float v = sq[i] / cnt - m * m;
  meanA[i] = m;
  rstdA[i] = rsqrtf(fmaxf(v, 0.f) + EPSI);
}

// ------- pre-normalize P half in place: P'[n] = (P[n] - mean[g]) * rstd[g], g = batch[n] ----
__global__ void __launch_bounds__(256) knorm1(unsigned short* __restrict__ PQb,
    const int* __restrict__ batch, const float* __restrict__ mean1,
    const float* __restrict__ rstd1, int N){
  int idx = blockIdx.x * 256 + threadIdx.x;
  if (idx >= N * 32) return;
  int n = idx >> 5, c8 = (idx & 31) * 8;
  int g = batch[n];
  unsigned short* pp = PQb + (size_t)n * 512 + c8;
  U8 pu; pu.q = *(const uint4*)pp;
  const float* mg = mean1 + g * 256 + c8;
  const float* rg = rstd1 + g * 256 + c8;
  float4 m0 = *(const float4*)mg, m1 = *(const float4*)(mg + 4);
  float4 r0 = *(const float4*)rg, r1 = *(const float4*)(rg + 4);
  U8 o;
  o.q.x = pk2((b2f(pu.u[0]) - m0.x) * r0.x, (b2f(pu.u[1]) - m0.y) * r0.y);
  o.q.y = pk2((b2f(pu.u[2]) - m0.z) * r0.z, (b2f(pu.u[3]) - m0.w) * r0.w);
  o.q.z = pk2((b2f(pu.u[4]) - m1.x) * r1.x, (b2f(pu.u[5]) - m1.y) * r1.y);
  o.q.w = pk2((b2f(pu.u[6]) - m1.z) * r1.z, (b2f(pu.u[7]) - m1.w) * r1.w);
  *(uint4*)pp = o.q;
}

// ------- fused: h1 = relu(P'[c] + Q[r]*rstd) -> GEMM2 -> y2 + fused stats2 ------------------
// Single-graph 32-edge tiles (padded). Persistent blocks + atomic tile queue (pop for next
// tile issued before current tile's compute so the atomic latency is hidden).
// Per-tile uniform rstd (broadcast); stats via cross-quad shuffle reduce + atomics.
__global__ void __launch_bounds__(256, 5) kmain(const unsigned short* __restrict__ PQb,
    const unsigned short* __restrict__ W2F, const int4* __restrict__ einfo,
    const float* __restrict__ rstd1, const float* __restrict__ b2,
    const unsigned int* __restrict__ hist, const unsigned int* __restrict__ gmeta,
    unsigned int* __restrict__ tilectr,
    unsigned short* __restrict__ y2b, float* __restrict__ sum2, float* __restrict__ sq2){
  __shared__ unsigned short Blds[4 * 8 * 64 * 8];  // 32 KiB, same layout as W2F
  {
    const uint4* src = (const uint4*)W2F;
    uint4* dst = (uint4*)Blds;
    for (int i = threadIdx.x; i < 2048; i += 256) dst[i] = src[i];
  }
  __syncthreads();  // only barrier in the kernel
  int lane = threadIdx.x & 63;
  int quad = lane >> 4, l15 = lane & 15;
  float b2v[4];
  #pragma unroll
  for (int cg = 0; cg < 4; ++cg) b2v[cg] = b2[cg * 16 + l15];
  int ntiles = (int)(gmeta[NG] >> 5);
  int t;
  if (lane == 0) t = (int)atomicAdd(tilectr, 1u);
  t = __builtin_amdgcn_readfirstlane(t);
  while (t < ntiles){
    int tn;
    if (lane == 0) tn = (int)atomicAdd(tilectr, 1u);  // prefetch next tile id
    tn = __builtin_amdgcn_readfirstlane(tn);
    int p0 = t * 32;
    int4 ev0 = einfo[p0 + l15];
    int4 ev1 = einfo[p0 + 16 + l15];
    int g = __builtin_amdgcn_readfirstlane(ev0.z);
    const unsigned short* pp0 = PQb + (size_t)ev0.x * 512 + quad * 8;
    const unsigned short* qq0 = PQb + (size_t)ev0.y * 512 + 256 + quad * 8;
    const unsigned short* pp1 = PQb + (size_t)ev1.x * 512 + quad * 8;
    const unsigned short* qq1 = PQb + (size_t)ev1.y * 512 + 256 + quad * 8;
    const float* rr = rstd1 + g * 256 + quad * 8;  // uniform per tile (broadcast loads)
    f32x4 acc[8];  // [sub*4 + cg]
    #pragma unroll
    for (int i = 0; i < 8; ++i){ acc[i][0]=0.f; acc[i][1]=0.f; acc[i][2]=0.f; acc[i][3]=0.f; }
    #pragma unroll 2
    for (int ks = 0; ks < 8; ++ks){
      U8 pu0, qu0, pu1, qu1;
      pu0.q = *(const uint4*)(pp0 + ks * 32);
      qu0.q = *(const uint4*)(qq0 + ks * 32);
      pu1.q = *(const uint4*)(pp1 + ks * 32);
      qu1.q = *(const uint4*)(qq1 + ks * 32);
      float4 ra = *(const float4*)(rr + ks * 32);
      float4 rb = *(const float4*)(rr + ks * 32 + 4);
      ABFrag a0, a1;
      a0.q.x = pk2(fmaxf(0.f, b2f(pu0.u[0]) + b2f(qu0.u[0]) * ra.x),
                   fmaxf(0.f, b2f(pu0.u[1]) + b2f(qu0.u[1]) * ra.y));
      a0.q.y = pk2(fmaxf(0.f, b2f(pu0.u[2]) + b2f(qu0.u[2]) * ra.z),
                   fmaxf(0.f, b2f(pu0.u[3]) + b2f(qu0.u[3]) * ra.w));
      a0.q.z = pk2(fmaxf(0.f, b2f(pu0.u[4]) + b2f(qu0.u[4]) * rb.x),
                   fmaxf(0.f, b2f(pu0.u[5]) + b2f(qu0.u[5]) * rb.y));
      a0.q.w = pk2(fmaxf(0.f, b2f(pu0.u[6]) + b2f(qu0.u[6]) * rb.z),
                   fmaxf(0.f, b2f(pu0.u[7]) + b2f(qu0.u[7]) * rb.w));
      a1.q.x = pk2(fmaxf(0.f, b2f(pu1.u[0]) + b2f(qu1.u[0]) * ra.x),
                   fmaxf(0.f, b2f(pu1.u[1]) + b2f(qu1.u[1]) * ra.y));
      a1.q.y = pk2(fmaxf(0.f, b2f(pu1.u[2]) + b2f(qu1.u[2]) * ra.z),
                   fmaxf(0.f, b2f(pu1.u[3]) + b2f(qu1.u[3]) * ra.w));
      a1.q.z = pk2(fmaxf(0.f, b2f(pu1.u[4]) + b2f(qu1.u[4]) * rb.x),
                   fmaxf(0.f, b2f(pu1.u[5]) + b2f(qu1.u[5]) * rb.y));
      a1.q.w = pk2(fmaxf(0.f, b2f(pu1.u[6]) + b2f(qu1.u[6]) * rb.z),
                   fmaxf(0.f, b2f(pu1.u[7]) + b2f(qu1.u[7]) * rb.w));
      #pragma unroll
      for (int cg = 0; cg < 4; ++cg){
        ABFrag b;
        b.q = *(const uint4*)&Blds[((cg * 8 + ks) * 64 + lane) * 8];
        acc[cg]     = __builtin_amdgcn_mfma_f32_16x16x32_bf16(a0.v, b.v, acc[cg], 0, 0, 0);
        acc[4 + cg] = __builtin_amdgcn_mfma_f32_16x16x32_bf16(a1.v, b.v, acc[4 + cg], 0, 0, 0);
      }
    }
    // epilogue: write y2 (bf16) + fused stats2 (f32, pads masked via real-count)
    int nl = (int)gmeta[g] + (int)hist[g] - p0;  // # real edges in this tile (may exceed 32)
    #pragma unroll
    for (int cg = 0; cg < 4; ++cg){
      float s = 0.f, qs = 0.f;
      #pragma unroll
      for (int sub = 0; sub < 2; ++sub)
        #pragma unroll
        for (int r = 0; r < 4; ++r){
          float y = acc[sub * 4 + cg][r] + b2v[cg];
          int el = sub * 16 + quad * 4 + r;
          y2b[(size_t)(p0 + el) * 64 + cg * 16 + l15] = f2b(y);
          if (el < nl){ s += y; qs = fmaf(y, y, qs); }
        }
      s  += __shfl_xor(s, 16);  s  += __shfl_xor(s, 32);
      qs += __shfl_xor(qs, 16); qs += __shfl_xor(qs, 32);
      if (quad == 0){
        atomicAdd(&sum2[g * 64 + cg * 16 + l15], s);
        atomicAdd(&sq2[g * 64 + cg * 16 + l15], qs);
      }
    }
    t = tn;
  }
}

// ------- final: norm+ReLU L2 -> GEMV W3 -> scatter; 8 lanes per edge + shuffle reduce -------
__global__ void kfinal(const unsigned short* __restrict__ y2b, const int4* __restrict__ einfo,
                       const unsigned int* __restrict__ gmeta,
                       const float* __restrict__ mean2, const float* __restrict__ rstd2,
                       const float* __restrict__ W3, const float* __restrict__ b3,
                       float* __restrict__ out){
  int EP = (int)gmeta[NG];
  int sub = threadIdx.x & 7;
  int c8 = sub * 8;
  float w3r[8];
  #pragma unroll
  for (int t = 0; t < 8; ++t) w3r[t] = W3[c8 + t];
  float b3v = b3[0];
  int step = (gridDim.x * blockDim.x) >> 3;
  for (int i = (blockIdx.x * blockDim.x + threadIdx.x) >> 3; i < EP; i += step){
    int4 ev = einfo[i];
    U8 yv; yv.q = *(const uint4*)(y2b + (size_t)i * 64 + c8);
    const float* mg = mean2 + ev.z * 64 + c8;
    const float* rg = rstd2 + ev.z * 64 + c8;
    float4 m0 = *(const float4*)mg, m1 = *(const float4*)(mg + 4);
    float4 r0 = *(const float4*)rg, r1 = *(const float4*)(rg + 4);
    float a = 0.f;
    a += fmaxf(0.f, (b2f(yv.u[0]) - m0.x) * r0.x) * w3r[0];
    a += fmaxf(0.f, (b2f(yv.u[1]) - m0.y) * r0.y) * w3r[1];
    a += fmaxf(0.f, (b2f(yv.u[2]) - m0.z) * r0.z) * w3r[2];
    a += fmaxf(0.f, (b2f(yv.u[3]) - m0.w) * r0.w) * w3r[3];
    a += fmaxf(0.f, (b2f(yv.u[4]) - m1.x) * r1.x) * w3r[4];
    a += fmaxf(0.f, (b2f(yv.u[5]) - m1.y) * r1.y) * w3r[5];
    a += fmaxf(0.f, (b2f(yv.u[6]) - m1.z) * r1.z) * w3r[6];
    a += fmaxf(0.f, (b2f(yv.u[7]) - m1.w) * r1.w) * w3r[7];
    a += __shfl_xor(a, 1);
    a += __shfl_xor(a, 2);
    a += __shfl_xor(a, 4);
    if (sub == 0 && ev.w >= 0) out[ev.w] = a + b3v;
  }
}

extern "C" void kernel_launch(void* const* d_in, const int* in_sizes, int n_in,
                              void* d_out, int out_size, void* d_ws, size_t ws_size,
                              hipStream_t stream){
  const float* emb  = (const float*)d_in[0];
  const int*   ei   = (const int*)d_in[1];
  const int*   batch= (const int*)d_in[2];
  const float* W1   = (const float*)d_in[3];
  const float* b1   = (const float*)d_in[4];
  const float* W2   = (const float*)d_in[5];
  const float* b2   = (const float*)d_in[6];
  const float* W3   = (const float*)d_in[7];
  const float* b3   = (const float*)d_in[8];
  int N = in_sizes[0] / 64;
  int E = in_sizes[1] / 2;
  int EPMAX = E + NG * 32;   // upper bound on padded edge count
  float* out = (float*)d_out;

  char* w = (char*)d_ws;
  size_t off = 0;
  auto nxt = [&](size_t bytes) -> char* {
    char* p = w + off;
    off = (off + bytes + 255) & ~(size_t)255;
    return p;
  };
  unsigned short* embb = (unsigned short*)nxt((size_t)N * 64 * 2);
  unsigned short* WcF  = (unsigned short*)nxt(32 * 2 * 64 * 8 * 2);
  unsigned short* W2F  = (unsigned short*)nxt(4 * 8 * 64 * 8 * 2);
  unsigned short* PQb  = (unsigned short*)nxt((size_t)N * 512 * 2);
  unsigned short* y2b  = (unsigned short*)nxt((size_t)EPMAX * 64 * 2);
  int4* einfo = (int4*)nxt((size_t)EPMAX * 16);
  float* mean1 = (float*)nxt(NG * 256 * 4);
  float* rstd1 = (float*)nxt(NG * 256 * 4);
  float* mean2 = (float*)nxt(NG * 64 * 4);
  float* rstd2 = (float*)nxt(NG * 64 * 4);
  unsigned int* ncursor = (unsigned int*)nxt((size_t)N * 4);
  unsigned int* gmeta   = (unsigned int*)nxt((NG + 1) * 4);
  // zero-init region (contiguous, one memset)
  char* zbase = w + off;
  unsigned int* hist  = (unsigned int*)nxt(NG * 4);
  unsigned int* nodeh = (unsigned int*)nxt((size_t)N * 4);
  unsigned int* tilectr = (unsigned int*)nxt(256);
  float* sum1 = (float*)nxt(NG * 256 * 4);
  float* sq1  = (float*)nxt(NG * 256 * 4);
  float* sum2 = (float*)nxt(NG * 64 * 4);
  float* sq2  = (float*)nxt(NG * 64 * 4);
  size_t zbytes = (size_t)((w + off) - zbase);
  hipMemsetAsync(zbase, 0, zbytes, stream);

  kprep<<<2048, 256, 0, stream>>>(emb, W1, W2, ei, batch, embb, WcF, W2F, hist, nodeh, N, E);
  kscan<<<NG, 256, 0, stream>>>(nodeh, hist, batch, ncursor, gmeta, N);
  kscatter<<<2048, 256, 0, stream>>>(ei, batch, E, ncursor, einfo);
  kpad<<<NG, 64, 0, stream>>>(einfo, hist, gmeta);
  {
    int tiles = ((N + 15) / 16) * 32;
    kgemm1<<<(tiles + 3) / 4, 256, 0, stream>>>(embb, WcF, b1, PQb, N);
  }
  kstats1<<<(EPMAX + 511) / 512, 256, 0, stream>>>(PQb, einfo, gmeta, sum1, sq1);
  kfin<<<(NG * 256 + 255) / 256, 256, 0, stream>>>(sum1, sq1, hist, mean1, rstd1, 256);
  knorm1<<<(N * 32 + 255) / 256, 256, 0, stream>>>(PQb, batch, mean1, rstd1, N);
  kmain<<<1280, 256, 0, stream>>>(PQb, W2F, einfo, rstd1, b2, hist, gmeta, tilectr,
                                  y2b, sum2, sq2);
  kfin<<<(NG * 64 + 255) / 256, 256, 0, stream>>>(sum2, sq2, hist, mean2, rstd2, 64);
  kfinal<<<2048, 256, 0, stream>>>(y2b, einfo, gmeta, mean2, rstd2, W3, b3, out);
}

// Round 6
// 505.582 us; speedup vs baseline: 1.5428x; 1.5428x over previous
//
#include <hip/hip_runtime.h>
#include <hip/hip_bf16.h>
#include <stdint.h>

#define NG 128
#define EPSI 1e-5f

typedef __attribute__((ext_vector_type(8))) __bf16 bf16x8;
typedef __attribute__((ext_vector_type(4))) float f32x4;

union ABFrag { bf16x8 v; unsigned short u[8]; uint4 q; };
union U8 { uint4 q; unsigned short u[8]; };

__device__ __forceinline__ float b2f(unsigned short u){
  union { unsigned int i; float f; } v; v.i = ((unsigned int)u) << 16; return v.f;
}
__device__ __forceinline__ unsigned short f2b(float f){
  union { float f; unsigned int i; } v; v.f = f;
  unsigned int r = v.i + 0x7fffu + ((v.i >> 16) & 1u);
  return (unsigned short)(r >> 16);
}
// pack 2 f32 -> 2 bf16 (RNE), lo in bits[15:0], hi in bits[31:16]
__device__ __forceinline__ unsigned int pk2(float lo, float hi){
  unsigned int r;
  asm("v_cvt_pk_bf16_f32 %0, %1, %2" : "=v"(r) : "v"(lo), "v"(hi));
  return r;
}

// ---------------- prep: bf16 conversions (frag order), graph hist, node hist ----------------
__global__ void kprep(const float* __restrict__ emb, const float* __restrict__ W1,
                      const float* __restrict__ W2,
                      const int* __restrict__ ei, const int* __restrict__ batch,
                      unsigned short* __restrict__ embb, unsigned short* __restrict__ WcF,
                      unsigned short* __restrict__ W2F, unsigned int* __restrict__ hist,
                      unsigned int* __restrict__ nodeh, int N, int E){
  __shared__ unsigned int h[NG];
  for (int i = threadIdx.x; i < NG; i += 256) h[i] = 0;
  __syncthreads();
  int idx = blockIdx.x * 256 + threadIdx.x;
  int stride = gridDim.x * 256;
  int embCnt4 = N * 16;  // float4 groups
  for (int i = idx; i < embCnt4; i += stride){
    float4 v = *(const float4*)(emb + (size_t)i * 4);
    ushort4 o; o.x = f2b(v.x); o.y = f2b(v.y); o.z = f2b(v.z); o.w = f2b(v.w);
    *(ushort4*)(embb + (size_t)i * 4) = o;
  }
  for (int i = idx; i < 32 * 2 * 64 * 8; i += stride){
    int j = i & 7, lane = (i >> 3) & 63, ks = (i >> 9) & 1, tn = i >> 10;
    int quad = lane >> 4, l15 = lane & 15;
    int k = ks * 32 + quad * 8 + j;
    int n = tn * 16 + l15;
    float wv = (n < 256) ? W1[k * 256 + n] : W1[(k + 64) * 256 + (n - 256)];
    WcF[i] = f2b(wv);
  }
  for (int i = idx; i < 4 * 8 * 64 * 8; i += stride){
    int j = i & 7, lane = (i >> 3) & 63, ks = (i >> 9) & 7, w = i >> 12;
    int quad = lane >> 4, l15 = lane & 15;
    W2F[i] = f2b(W2[(ks * 32 + quad * 8 + j) * 64 + w * 16 + l15]);
  }
  for (int e = idx; e < E; e += stride){
    int cn = ei[e];
    atomicAdd(&h[batch[cn]], 1u);
    atomicAdd(&nodeh[cn], 1u);
  }
  __syncthreads();
  for (int i = threadIdx.x; i < NG; i += 256)
    if (h[i]) atomicAdd(&hist[i], h[i]);
}

// --- scan: one block per graph. Computes padded-base prefix (pbase) from hist,
//     binary-searches this graph's node range in sorted batch, then exclusive-scans
//     nodeh over that range into ncursor (= pbase + local prefix). ---
__global__ void __launch_bounds__(256) kscan(const unsigned int* __restrict__ nodeh,
                      const unsigned int* __restrict__ hist,
                      const int* __restrict__ batch,
                      unsigned int* __restrict__ ncursor,
                      unsigned int* __restrict__ gmeta, int N){
  __shared__ unsigned int sh[3];     // pbase, lo, hi
  __shared__ unsigned int wtot[4];
  int g = blockIdx.x;
  int t = threadIdx.x;
  // padded-count prefix over graphs < g (redundant per block; trivial work)
  unsigned int part = 0;
  for (int i = t; i < g; i += 256) part += (hist[i] + 31u) & ~31u;
  #pragma unroll
  for (int d = 1; d < 64; d <<= 1) part += __shfl_xor(part, d);
  if ((t & 63) == 0) wtot[t >> 6] = part;
  // node range via binary search on sorted batch
  if (t == 64 || t == 65){
    int target = g + (t - 64);
    int lo = 0, hi = N;
    while (lo < hi){ int mid = (lo + hi) >> 1; if (batch[mid] < target) lo = mid + 1; else hi = mid; }
    sh[1 + (t - 64)] = lo;
  }
  __syncthreads();
  if (t == 0){
    unsigned int pb = wtot[0] + wtot[1] + wtot[2] + wtot[3];
    sh[0] = pb;
    gmeta[g] = pb;
    if (g == NG - 1) gmeta[NG] = pb + ((hist[g] + 31u) & ~31u);
  }
  __syncthreads();
  unsigned int run = sh[0];
  int lo = (int)sh[1], hi = (int)sh[2];
  int wid = t >> 6;
  for (int base = lo; base < hi; base += 256){
    int i = base + t;
    unsigned int v = (i < hi) ? nodeh[i] : 0u;
    unsigned int x = v;
    #pragma unroll
    for (int d = 1; d < 64; d <<= 1){
      unsigned int y = __shfl_up(x, d);
      if ((t & 63) >= d) x += y;
    }
    if ((t & 63) == 63) wtot[wid] = x;
    __syncthreads();
    unsigned int woff = 0;
    #pragma unroll
    for (int wb = 0; wb < 4; ++wb) if (wb < wid) woff += wtot[wb];
    if (i < hi) ncursor[i] = run + woff + x - v;
    run += wtot[0] + wtot[1] + wtot[2] + wtot[3];
    __syncthreads();
  }
}

// einfo[p] = {col_node, row_node, graph, orig_edge}, p sorted by col node (=> by graph),
// graph segments padded to multiples of 32.
__global__ void kscatter(const int* __restrict__ ei, const int* __restrict__ batch, int E,
                         unsigned int* __restrict__ ncursor, int4* __restrict__ einfo){
  int idx = blockIdx.x * 256 + threadIdx.x;
  for (int e = idx; e < E; e += gridDim.x * 256){
    int cn = ei[e], rn = ei[E + e];
    int g = batch[cn];
    unsigned int p = atomicAdd(&ncursor[cn], 1u);
    einfo[p] = make_int4(cn, rn, g, e);
  }
}

// fill pad slots with a copy of the graph's first edge, orig = -1 (one block per graph)
__global__ void kpad(int4* __restrict__ einfo, const unsigned int* __restrict__ hist,
                     const unsigned int* __restrict__ gmeta){
  int g = blockIdx.x;
  unsigned int cnt = hist[g];
  if (!cnt) return;
  unsigned int pe = (cnt + 31u) & ~31u;
  if (cnt == pe) return;
  unsigned int base = gmeta[g];
  int4 e0 = einfo[base]; e0.w = -1;
  for (unsigned int i = cnt + threadIdx.x; i < pe; i += 64)
    einfo[base + i] = e0;
}

// ---------------- GEMM1: PQ[N,512] = embb[N,64] @ W1cat[64,512] (+b1 on P cols) --------------
// One wave per 16-row m-tile; loops all 32 n-tiles with A-fragments held in registers.
__global__ void __launch_bounds__(256) kgemm1(const unsigned short* __restrict__ embb,
    const unsigned short* __restrict__ WcF, const float* __restrict__ b1,
    unsigned short* __restrict__ PQb, int Nn){
  int wave = threadIdx.x >> 6, lane = threadIdx.x & 63;
  int quad = lane >> 4, l15 = lane & 15;
  int tm = blockIdx.x * 4 + wave;
  int tmmax = (Nn + 15) >> 4;
  if (tm >= tmmax) return;
  int m = tm * 16 + l15; if (m >= Nn) m = Nn - 1;
  ABFrag a0, a1;
  a0.q = *(const uint4*)(embb + (size_t)m * 64 + quad * 8);
  a1.q = *(const uint4*)(embb + (size_t)m * 64 + 32 + quad * 8);
  int rowbase = tm * 16 + quad * 4;
  #pragma unroll 4
  for (int tn = 0; tn < 32; ++tn){
    ABFrag b0, b1f;
    b0.q  = *(const uint4*)(WcF + ((size_t)(tn * 2 + 0) * 64 + lane) * 8);
    b1f.q = *(const uint4*)(WcF + ((size_t)(tn * 2 + 1) * 64 + lane) * 8);
    f32x4 acc = {0.f, 0.f, 0.f, 0.f};
    acc = __builtin_amdgcn_mfma_f32_16x16x32_bf16(a0.v, b0.v, acc, 0, 0, 0);
    acc = __builtin_amdgcn_mfma_f32_16x16x32_bf16(a1.v, b1f.v, acc, 0, 0, 0);
    int col = tn * 16 + l15;
    float bias = (col < 256) ? b1[col] : 0.0f;
    #pragma unroll
    for (int r = 0; r < 4; ++r){
      int rowg = rowbase + r;
      if (rowg < Nn) PQb[(size_t)rowg * 512 + col] = f2b(acc[r] + bias);
    }
  }
}

// ------- stats over y1 = P[col]+Q[row]; contiguous 512-edge chunk/block, LDS accumulate -----
// 4 edges in flight per thread (8 gathers) for memory-level parallelism.
__global__ void __launch_bounds__(256) kstats1(const unsigned short* __restrict__ PQb,
                        const int4* __restrict__ einfo, const unsigned int* __restrict__ gmeta,
                        float* __restrict__ sum1, float* __restrict__ sq1){
  __shared__ float lsum[8][256];
  __shared__ float lsq[8][256];
  int tid = threadIdx.x;
  int EP = (int)gmeta[NG];
  int i0 = blockIdx.x * 512;
  if (i0 >= EP) return;
  for (int i = tid; i < 8 * 256; i += 256){ ((float*)lsum)[i] = 0.f; ((float*)lsq)[i] = 0.f; }
  __syncthreads();
  int i1 = min(EP, i0 + 512);
  int gfirst = einfo[i0].z;
  int eo = tid >> 5;          // 8 edge slots
  int c8 = (tid & 31) * 8;    // 8-channel slice
  float s[8], q[8];
  #pragma unroll
  for (int t = 0; t < 8; ++t){ s[t] = 0.f; q[t] = 0.f; }
  int cur = -1;
  auto flushreg = [&](){
    if (cur >= 0){
      unsigned slot = (unsigned)(cur - gfirst);
      if (slot < 8u){
        #pragma unroll
        for (int t = 0; t < 8; ++t){
          atomicAdd(&lsum[slot][c8 + t], s[t]);
          atomicAdd(&lsq[slot][c8 + t], q[t]);
        }
      } else {
        #pragma unroll
        for (int t = 0; t < 8; ++t){
          atomicAdd(&sum1[cur * 256 + c8 + t], s[t]);
          atomicAdd(&sq1[cur * 256 + c8 + t], q[t]);
        }
      }
      #pragma unroll
      for (int t = 0; t < 8; ++t){ s[t] = 0.f; q[t] = 0.f; }
    }
  };
  auto accum = [&](const U8& pu, const U8& qu){
    #pragma unroll
    for (int t = 0; t < 8; ++t){
      float y = b2f(pu.u[t]) + b2f(qu.u[t]);
      s[t] += y; q[t] += y * y;
    }
  };
  for (int p = i0 + eo; p < i1; p += 32){
    int4 ev0 = einfo[p];
    int pa = p + 8, pb = p + 16, pc = p + 24;
    int4 ev1 = (pa < i1) ? einfo[pa] : make_int4(0, 0, -1, -1);
    int4 ev2 = (pb < i1) ? einfo[pb] : make_int4(0, 0, -1, -1);
    int4 ev3 = (pc < i1) ? einfo[pc] : make_int4(0, 0, -1, -1);
    U8 pu0, qu0, pu1, qu1, pu2, qu2, pu3, qu3;
    pu0.q = *(const uint4*)(PQb + (size_t)ev0.x * 512 + c8);
    qu0.q = *(const uint4*)(PQb + (size_t)ev0.y * 512 + 256 + c8);
    pu1.q = *(const uint4*)(PQb + (size_t)ev1.x * 512 + c8);
    qu1.q = *(const uint4*)(PQb + (size_t)ev1.y * 512 + 256 + c8);
    pu2.q = *(const uint4*)(PQb + (size_t)ev2.x * 512 + c8);
    qu2.q = *(const uint4*)(PQb + (size_t)ev2.y * 512 + 256 + c8);
    pu3.q = *(const uint4*)(PQb + (size_t)ev3.x * 512 + c8);
    qu3.q = *(const uint4*)(PQb + (size_t)ev3.y * 512 + 256 + c8);
    if (ev0.z != cur){ flushreg(); cur = ev0.z; }
    if (ev0.w >= 0) accum(pu0, qu0);
    if (ev1.z >= 0){
      if (ev1.z != cur){ flushreg(); cur = ev1.z; }
      if (ev1.w >= 0) accum(pu1, qu1);
    }
    if (ev2.z >= 0){
      if (ev2.z != cur){ flushreg(); cur = ev2.z; }
      if (ev2.w >= 0) accum(pu2, qu2);
    }
    if (ev3.z >= 0){
      if (ev3.z != cur){ flushreg(); cur = ev3.z; }
      if (ev3.w >= 0) accum(pu3, qu3);
    }
  }
  flushreg();
  __syncthreads();
  for (int i = tid; i < 8 * 256; i += 256){
    int slot = i >> 8, ch = i & 255;
    float vs = lsum[slot][ch], vq = lsq[slot][ch];
    if (vs != 0.f || vq != 0.f){
      int g = gfirst + slot;
      atomicAdd(&sum1[g * 256 + ch], vs);
      atomicAdd(&sq1[g * 256 + ch], vq);
    }
  }
}

__global__ void kfin(const float* __restrict__ sum, const float* __restrict__ sq,
                     const unsigned int* __restrict__ hist,
                     float* __restrict__ meanA, float* __restrict__ rstdA, int C){
  int i = blockIdx.x * blockDim.x + threadIdx.x;
  if (i >= NG * C) return;
  int g = i / C;
  float cnt = fmaxf((float)hist[g], 1.0f);
  float m = sum[i] / cnt;
  float v = sq[i] / cnt - m * m;
  meanA[i] = m;
  rstdA[i] = rsqrtf(fmaxf(v, 0.f) + EPSI);
}

// ------- pre-normalize P half in place: P'[n] = (P[n] - mean[g]) * rstd[g], g = batch[n] ----
__global__ void __launch_bounds__(256) knorm1(unsigned short* __restrict__ PQb,
    const int* __restrict__ batch, const float* __restrict__ mean1,
    const float* __restrict__ rstd1, int N){
  int idx = blockIdx.x * 256 + threadIdx.x;
  if (idx >= N * 32) return;
  int n = idx >> 5, c8 = (idx & 31) * 8;
  int g = batch[n];
  unsigned short* pp = PQb + (size_t)n * 512 + c8;
  U8 pu; pu.q = *(const uint4*)pp;
  const float* mg = mean1 + g * 256 + c8;
  const float* rg = rstd1 + g * 256 + c8;
  float4 m0 = *(const float4*)mg, m1 = *(const float4*)(mg + 4);
  float4 r0 = *(const float4*)rg, r1 = *(const float4*)(rg + 4);
  U8 o;
  o.q.x = pk2((b2f(pu.u[0]) - m0.x) * r0.x, (b2f(pu.u[1]) - m0.y) * r0.y);
  o.q.y = pk2((b2f(pu.u[2]) - m0.z) * r0.z, (b2f(pu.u[3]) - m0.w) * r0.w);
  o.q.z = pk2((b2f(pu.u[4]) - m1.x) * r1.x, (b2f(pu.u[5]) - m1.y) * r1.y);
  o.q.w = pk2((b2f(pu.u[6]) - m1.z) * r1.z, (b2f(pu.u[7]) - m1.w) * r1.w);
  *(uint4*)pp = o.q;
}

// ------- fused: h1 = relu(P'[c] + Q[r]*rstd) -> GEMM2 -> y2 + fused stats2 ------------------
// Single-graph 32-edge tiles (padded). Barrier-free main loop; per-tile uniform rstd;
// stats accumulated from f32 accumulators via cross-quad shuffle reduce + atomics.
__global__ void __launch_bounds__(256, 5) kmain(const unsigned short* __restrict__ PQb,
    const unsigned short* __restrict__ W2F, const int4* __restrict__ einfo,
    const float* __restrict__ rstd1, const float* __restrict__ b2,
    const unsigned int* __restrict__ hist, const unsigned int* __restrict__ gmeta,
    unsigned short* __restrict__ y2b, float* __restrict__ sum2, float* __restrict__ sq2){
  __shared__ unsigned short Blds[4 * 8 * 64 * 8];  // 32 KiB, same layout as W2F
  {
    const uint4* src = (const uint4*)W2F;
    uint4* dst = (uint4*)Blds;
    for (int i = threadIdx.x; i < 2048; i += 256) dst[i] = src[i];
  }
  __syncthreads();  // only barrier in the kernel
  int wave = threadIdx.x >> 6, lane = threadIdx.x & 63;
  int quad = lane >> 4, l15 = lane & 15;
  float b2v[4];
  #pragma unroll
  for (int cg = 0; cg < 4; ++cg) b2v[cg] = b2[cg * 16 + l15];
  int ntiles = (int)(gmeta[NG] >> 5);
  int nw = gridDim.x * 4;
  for (int t = blockIdx.x * 4 + wave; t < ntiles; t += nw){
    int p0 = t * 32;
    int4 ev0 = einfo[p0 + l15];
    int4 ev1 = einfo[p0 + 16 + l15];
    int g = __builtin_amdgcn_readfirstlane(ev0.z);
    const unsigned short* pp0 = PQb + (size_t)ev0.x * 512 + quad * 8;
    const unsigned short* qq0 = PQb + (size_t)ev0.y * 512 + 256 + quad * 8;
    const unsigned short* pp1 = PQb + (size_t)ev1.x * 512 + quad * 8;
    const unsigned short* qq1 = PQb + (size_t)ev1.y * 512 + 256 + quad * 8;
    const float* rr = rstd1 + g * 256 + quad * 8;  // uniform per tile (broadcast loads)
    f32x4 acc[8];  // [sub*4 + cg]
    #pragma unroll
    for (int i = 0; i < 8; ++i){ acc[i][0]=0.f; acc[i][1]=0.f; acc[i][2]=0.f; acc[i][3]=0.f; }
    #pragma unroll 2
    for (int ks = 0; ks < 8; ++ks){
      U8 pu0, qu0, pu1, qu1;
      pu0.q = *(const uint4*)(pp0 + ks * 32);
      qu0.q = *(const uint4*)(qq0 + ks * 32);
      pu1.q = *(const uint4*)(pp1 + ks * 32);
      qu1.q = *(const uint4*)(qq1 + ks * 32);
      float4 ra = *(const float4*)(rr + ks * 32);
      float4 rb = *(const float4*)(rr + ks * 32 + 4);
      ABFrag a0, a1;
      a0.q.x = pk2(fmaxf(0.f, b2f(pu0.u[0]) + b2f(qu0.u[0]) * ra.x),
                   fmaxf(0.f, b2f(pu0.u[1]) + b2f(qu0.u[1]) * ra.y));
      a0.q.y = pk2(fmaxf(0.f, b2f(pu0.u[2]) + b2f(qu0.u[2]) * ra.z),
                   fmaxf(0.f, b2f(pu0.u[3]) + b2f(qu0.u[3]) * ra.w));
      a0.q.z = pk2(fmaxf(0.f, b2f(pu0.u[4]) + b2f(qu0.u[4]) * rb.x),
                   fmaxf(0.f, b2f(pu0.u[5]) + b2f(qu0.u[5]) * rb.y));
      a0.q.w = pk2(fmaxf(0.f, b2f(pu0.u[6]) + b2f(qu0.u[6]) * rb.z),
                   fmaxf(0.f, b2f(pu0.u[7]) + b2f(qu0.u[7]) * rb.w));
      a1.q.x = pk2(fmaxf(0.f, b2f(pu1.u[0]) + b2f(qu1.u[0]) * ra.x),
                   fmaxf(0.f, b2f(pu1.u[1]) + b2f(qu1.u[1]) * ra.y));
      a1.q.y = pk2(fmaxf(0.f, b2f(pu1.u[2]) + b2f(qu1.u[2]) * ra.z),
                   fmaxf(0.f, b2f(pu1.u[3]) + b2f(qu1.u[3]) * ra.w));
      a1.q.z = pk2(fmaxf(0.f, b2f(pu1.u[4]) + b2f(qu1.u[4]) * rb.x),
                   fmaxf(0.f, b2f(pu1.u[5]) + b2f(qu1.u[5]) * rb.y));
      a1.q.w = pk2(fmaxf(0.f, b2f(pu1.u[6]) + b2f(qu1.u[6]) * rb.z),
                   fmaxf(0.f, b2f(pu1.u[7]) + b2f(qu1.u[7]) * rb.w));
      #pragma unroll
      for (int cg = 0; cg < 4; ++cg){
        ABFrag b;
        b.q = *(const uint4*)&Blds[((cg * 8 + ks) * 64 + lane) * 8];
        acc[cg]     = __builtin_amdgcn_mfma_f32_16x16x32_bf16(a0.v, b.v, acc[cg], 0, 0, 0);
        acc[4 + cg] = __builtin_amdgcn_mfma_f32_16x16x32_bf16(a1.v, b.v, acc[4 + cg], 0, 0, 0);
      }
    }
    // epilogue: write y2 (bf16) + fused stats2 (f32, pads masked via real-count)
    int nl = (int)gmeta[g] + (int)hist[g] - p0;  // # real edges in this tile (may exceed 32)
    #pragma unroll
    for (int cg = 0; cg < 4; ++cg){
      float s = 0.f, qs = 0.f;
      #pragma unroll
      for (int sub = 0; sub < 2; ++sub)
        #pragma unroll
        for (int r = 0; r < 4; ++r){
          float y = acc[sub * 4 + cg][r] + b2v[cg];
          int el = sub * 16 + quad * 4 + r;
          y2b[(size_t)(p0 + el) * 64 + cg * 16 + l15] = f2b(y);
          if (el < nl){ s += y; qs = fmaf(y, y, qs); }
        }
      s  += __shfl_xor(s, 16);  s  += __shfl_xor(s, 32);
      qs += __shfl_xor(qs, 16); qs += __shfl_xor(qs, 32);
      if (quad == 0){
        atomicAdd(&sum2[g * 64 + cg * 16 + l15], s);
        atomicAdd(&sq2[g * 64 + cg * 16 + l15], qs);
      }
    }
  }
}

// ------- final: norm+ReLU L2 -> GEMV W3 -> scatter; 8 lanes per edge + shuffle reduce -------
__global__ void kfinal(const unsigned short* __restrict__ y2b, const int4* __restrict__ einfo,
                       const unsigned int* __restrict__ gmeta,
                       const float* __restrict__ mean2, const float* __restrict__ rstd2,
                       const float* __restrict__ W3, const float* __restrict__ b3,
                       float* __restrict__ out){
  int EP = (int)gmeta[NG];
  int sub = threadIdx.x & 7;
  int c8 = sub * 8;
  float w3r[8];
  #pragma unroll
  for (int t = 0; t < 8; ++t) w3r[t] = W3[c8 + t];
  float b3v = b3[0];
  int step = (gridDim.x * blockDim.x) >> 3;
  for (int i = (blockIdx.x * blockDim.x + threadIdx.x) >> 3; i < EP; i += step){
    int4 ev = einfo[i];
    U8 yv; yv.q = *(const uint4*)(y2b + (size_t)i * 64 + c8);
    const float* mg = mean2 + ev.z * 64 + c8;
    const float* rg = rstd2 + ev.z * 64 + c8;
    float4 m0 = *(const float4*)mg, m1 = *(const float4*)(mg + 4);
    float4 r0 = *(const float4*)rg, r1 = *(const float4*)(rg + 4);
    float a = 0.f;
    a += fmaxf(0.f, (b2f(yv.u[0]) - m0.x) * r0.x) * w3r[0];
    a += fmaxf(0.f, (b2f(yv.u[1]) - m0.y) * r0.y) * w3r[1];
    a += fmaxf(0.f, (b2f(yv.u[2]) - m0.z) * r0.z) * w3r[2];
    a += fmaxf(0.f, (b2f(yv.u[3]) - m0.w) * r0.w) * w3r[3];
    a += fmaxf(0.f, (b2f(yv.u[4]) - m1.x) * r1.x) * w3r[4];
    a += fmaxf(0.f, (b2f(yv.u[5]) - m1.y) * r1.y) * w3r[5];
    a += fmaxf(0.f, (b2f(yv.u[6]) - m1.z) * r1.z) * w3r[6];
    a += fmaxf(0.f, (b2f(yv.u[7]) - m1.w) * r1.w) * w3r[7];
    a += __shfl_xor(a, 1);
    a += __shfl_xor(a, 2);
    a += __shfl_xor(a, 4);
    if (sub == 0 && ev.w >= 0) out[ev.w] = a + b3v;
  }
}

extern "C" void kernel_launch(void* const* d_in, const int* in_sizes, int n_in,
                              void* d_out, int out_size, void* d_ws, size_t ws_size,
                              hipStream_t stream){
  const float* emb  = (const float*)d_in[0];
  const int*   ei   = (const int*)d_in[1];
  const int*   batch= (const int*)d_in[2];
  const float* W1   = (const float*)d_in[3];
  const float* b1   = (const float*)d_in[4];
  const float* W2   = (const float*)d_in[5];
  const float* b2   = (const float*)d_in[6];
  const float* W3   = (const float*)d_in[7];
  const float* b3   = (const float*)d_in[8];
  int N = in_sizes[0] / 64;
  int E = in_sizes[1] / 2;
  int EPMAX = E + NG * 32;   // upper bound on padded edge count
  float* out = (float*)d_out;

  char* w = (char*)d_ws;
  size_t off = 0;
  auto nxt = [&](size_t bytes) -> char* {
    char* p = w + off;
    off = (off + bytes + 255) & ~(size_t)255;
    return p;
  };
  unsigned short* embb = (unsigned short*)nxt((size_t)N * 64 * 2);
  unsigned short* WcF  = (unsigned short*)nxt(32 * 2 * 64 * 8 * 2);
  unsigned short* W2F  = (unsigned short*)nxt(4 * 8 * 64 * 8 * 2);
  unsigned short* PQb  = (unsigned short*)nxt((size_t)N * 512 * 2);
  unsigned short* y2b  = (unsigned short*)nxt((size_t)EPMAX * 64 * 2);
  int4* einfo = (int4*)nxt((size_t)EPMAX * 16);
  float* mean1 = (float*)nxt(NG * 256 * 4);
  float* rstd1 = (float*)nxt(NG * 256 * 4);
  float* mean2 = (float*)nxt(NG * 64 * 4);
  float* rstd2 = (float*)nxt(NG * 64 * 4);
  unsigned int* ncursor = (unsigned int*)nxt((size_t)N * 4);
  unsigned int* gmeta   = (unsigned int*)nxt((NG + 1) * 4);
  // zero-init region (contiguous, one memset)
  char* zbase = w + off;
  unsigned int* hist  = (unsigned int*)nxt(NG * 4);
  unsigned int* nodeh = (unsigned int*)nxt((size_t)N * 4);
  float* sum1 = (float*)nxt(NG * 256 * 4);
  float* sq1  = (float*)nxt(NG * 256 * 4);
  float* sum2 = (float*)nxt(NG * 64 * 4);
  float* sq2  = (float*)nxt(NG * 64 * 4);
  size_t zbytes = (size_t)((w + off) - zbase);
  hipMemsetAsync(zbase, 0, zbytes, stream);

  kprep<<<2048, 256, 0, stream>>>(emb, W1, W2, ei, batch, embb, WcF, W2F, hist, nodeh, N, E);
  kscan<<<NG, 256, 0, stream>>>(nodeh, hist, batch, ncursor, gmeta, N);
  kscatter<<<2048, 256, 0, stream>>>(ei, batch, E, ncursor, einfo);
  kpad<<<NG, 64, 0, stream>>>(einfo, hist, gmeta);
  {
    int tmmax = (N + 15) / 16;
    kgemm1<<<(tmmax + 3) / 4, 256, 0, stream>>>(embb, WcF, b1, PQb, N);
  }
  kstats1<<<(EPMAX + 511) / 512, 256, 0, stream>>>(PQb, einfo, gmeta, sum1, sq1);
  kfin<<<(NG * 256 + 255) / 256, 256, 0, stream>>>(sum1, sq1, hist, mean1, rstd1, 256);
  knorm1<<<(N * 32 + 255) / 256, 256, 0, stream>>>(PQb, batch, mean1, rstd1, N);
  kmain<<<2048, 256, 0, stream>>>(PQb, W2F, einfo, rstd1, b2, hist, gmeta, y2b, sum2, sq2);
  kfin<<<(NG * 64 + 255) / 256, 256, 0, stream>>>(sum2, sq2, hist, mean2, rstd2, 64);
  kfinal<<<2048, 256, 0, stream>>>(y2b, einfo, gmeta, mean2, rstd2, W3, b3, out);
}